// Round 1
// baseline (3284.067 us; speedup 1.0000x reference)
//
#include <hip/hip_runtime.h>
#include <stdint.h>

typedef __attribute__((ext_vector_type(8))) short bf16x8;
typedef __attribute__((ext_vector_type(4))) float f32x4;
typedef unsigned short ushort_t;

__device__ __forceinline__ ushort_t f2bf(float f) {
    union { float f; unsigned u; } v; v.f = f;
    unsigned u = v.u;
    return (ushort_t)((u + 0x7FFFu + ((u >> 16) & 1u)) >> 16);
}
__device__ __forceinline__ float bf2f(ushort_t h) {
    union { unsigned u; float f; } v; v.u = ((unsigned)h) << 16;
    return v.f;
}
__device__ __forceinline__ f32x4 mfma16(bf16x8 a, bf16x8 b, f32x4 c) {
    return __builtin_amdgcn_mfma_f32_16x16x32_bf16(a, b, c, 0, 0, 0);
}

// ---------------------------------------------------------------------------
// Prep: build bf16 transposed weight layouts Bt[n][k] (K-contiguous rows).
// BtA [256][128] = [W1|W2]^T ; BtE [128][160] = [W3;We;0]^T ;
// BtM1 [256][128] ; BtM2 [256][256] ; BtM3 [128][256]
// ---------------------------------------------------------------------------
__global__ __launch_bounds__(256) void prep_k(
    const float* __restrict__ W1, const float* __restrict__ W2,
    const float* __restrict__ W3, const float* __restrict__ We,
    const float* __restrict__ Wm1, const float* __restrict__ Wm2,
    const float* __restrict__ Wm3,
    ushort_t* __restrict__ BtA, ushort_t* __restrict__ BtE,
    ushort_t* __restrict__ BtM1, ushort_t* __restrict__ BtM2,
    ushort_t* __restrict__ BtM3)
{
    int t = blockIdx.x * 256 + threadIdx.x;
    if (t < 32768) {                       // BtA
        int n = t >> 7, k = t & 127;
        float v = (n < 128) ? W1[k * 128 + n] : W2[k * 128 + (n - 128)];
        BtA[t] = f2bf(v);
        return;
    }
    t -= 32768;
    if (t < 20480) {                       // BtE
        int n = t / 160, k = t % 160;
        float v = 0.f;
        if (k < 128) v = W3[k * 128 + n];
        else if (k < 144) v = We[(k - 128) * 128 + n];
        BtE[n * 160 + k] = f2bf(v);
        return;
    }
    t -= 20480;
    if (t < 32768) {                       // BtM1
        int n = t >> 7, k = t & 127;
        BtM1[t] = f2bf(Wm1[k * 256 + n]);
        return;
    }
    t -= 32768;
    if (t < 65536) {                       // BtM2
        int n = t >> 8, k = t & 255;
        BtM2[t] = f2bf(Wm2[k * 256 + n]);
        return;
    }
    t -= 65536;
    if (t < 32768) {                       // BtM3
        int n = t >> 8, k = t & 255;
        BtM3[t] = f2bf(Wm3[k * 128 + n]);
        return;
    }
}

// ---------------------------------------------------------------------------
// Generic skinny GEMM: Out[M,NCOLS] = A[M,K] @ Bt^T, block = 64 rows x NCOLS.
// AMODE 0: A fp32 plain. AMODE 1: A bf16 with relu(af_a*x+af_c) applied.
// STATS: per-column sum/sumsq into 64 slots. OUTF32: fp32 out + bias.
// ---------------------------------------------------------------------------
template <int KTILES, int NCOLS, int AMODE, bool STATS, bool OUTF32>
__global__ __launch_bounds__(256) void gemm_k(
    const void* __restrict__ Ap, const ushort_t* __restrict__ Bt,
    void* __restrict__ Out,
    const float* __restrict__ af_a, const float* __restrict__ af_c,
    const float* __restrict__ bias,
    float* __restrict__ st_sum, float* __restrict__ st_sq, int M)
{
    constexpr int K = KTILES * 32;
    constexpr int NT = NCOLS / 16;
    const int tid = threadIdx.x;
    const int lane = tid & 63;
    const int w = tid >> 6;
    const int l16 = lane & 15;
    const int lg = lane >> 4;
    const long base = (long)blockIdx.x * 64;
    const int arow = (int)base + w * 16 + l16;
    const bool aval = arow < M;

    f32x4 acc[NT];
#pragma unroll
    for (int i = 0; i < NT; i++) acc[i] = f32x4{0.f, 0.f, 0.f, 0.f};

#pragma unroll
    for (int s = 0; s < KTILES; s++) {
        const int kb = s * 32 + lg * 8;
        bf16x8 af = bf16x8{0, 0, 0, 0, 0, 0, 0, 0};
        if constexpr (AMODE == 0) {
            if (aval) {
                const float* A = (const float*)Ap;
                const f32x4* p = (const f32x4*)(A + (long)arow * K + kb);
                f32x4 x0 = p[0], x1 = p[1];
                ushort_t* o = (ushort_t*)&af;
#pragma unroll
                for (int j = 0; j < 4; j++) { o[j] = f2bf(x0[j]); o[4 + j] = f2bf(x1[j]); }
            }
        } else {
            if (aval) {
                const ushort_t* A = (const ushort_t*)Ap;
                bf16x8 raw = *(const bf16x8*)(A + (long)arow * K + kb);
                const ushort_t* ri = (const ushort_t*)&raw;
                f32x4 aa0 = *(const f32x4*)(af_a + kb);
                f32x4 aa1 = *(const f32x4*)(af_a + kb + 4);
                f32x4 cc0 = *(const f32x4*)(af_c + kb);
                f32x4 cc1 = *(const f32x4*)(af_c + kb + 4);
                ushort_t* o = (ushort_t*)&af;
#pragma unroll
                for (int j = 0; j < 4; j++) {
                    float t0 = aa0[j] * bf2f(ri[j]) + cc0[j];
                    float t1 = aa1[j] * bf2f(ri[4 + j]) + cc1[j];
                    o[j] = f2bf(t0 > 0.f ? t0 : 0.f);
                    o[4 + j] = f2bf(t1 > 0.f ? t1 : 0.f);
                }
            }
        }
#pragma unroll
        for (int ct = 0; ct < NT; ct++) {
            const int n = ct * 16 + l16;
            bf16x8 bf = *(const bf16x8*)(Bt + (long)n * K + kb);
            acc[ct] = mfma16(af, bf, acc[ct]);
        }
    }

    const int orow0 = (int)base + w * 16 + lg * 4;
#pragma unroll
    for (int ct = 0; ct < NT; ct++) {
        const int n = ct * 16 + l16;
        float ssum = 0.f, ssq = 0.f;
#pragma unroll
        for (int r = 0; r < 4; r++) {
            const int m = orow0 + r;
            if (m < M) {
                const float v = acc[ct][r];
                if constexpr (OUTF32) {
                    ((float*)Out)[(long)m * NCOLS + n] = v + bias[n];
                } else {
                    ((ushort_t*)Out)[(long)m * NCOLS + n] = f2bf(v);
                }
                if constexpr (STATS) { ssum += v; ssq += v * v; }
            }
        }
        if constexpr (STATS) {
            ssum += __shfl_xor(ssum, 16);
            ssum += __shfl_xor(ssum, 32);
            ssq  += __shfl_xor(ssq, 16);
            ssq  += __shfl_xor(ssq, 32);
            if (lg == 0) {
                const int slot = blockIdx.x & 63;
                atomicAdd(&st_sum[slot * NCOLS + n], ssum);
                atomicAdd(&st_sq[slot * NCOLS + n], ssq);
            }
        }
    }
}

// ---------------------------------------------------------------------------
// Edge kernel: msg[e] = edge_rep@W3 + edge_attr@We + be + n1[src] + n2[dst]
// (K=160 padded MFMA), store bf16 msg, accumulate BN0 stats.
// ---------------------------------------------------------------------------
__global__ __launch_bounds__(256) void edge_k(
    const float* __restrict__ edge_rep, const float* __restrict__ edge_attr,
    const int* __restrict__ ei, const ushort_t* __restrict__ n12,
    const ushort_t* __restrict__ BtE, const float* __restrict__ be,
    ushort_t* __restrict__ msg,
    float* __restrict__ st_sum, float* __restrict__ st_sq, long E)
{
    __shared__ float tile[64][130];
    const int tid = threadIdx.x;
    const int lane = tid & 63;
    const int w = tid >> 6;
    const int l16 = lane & 15;
    const int lg = lane >> 4;
    const long base = (long)blockIdx.x * 64;
    const long arow = base + w * 16 + l16;
    const bool aval = arow < E;

    f32x4 acc[8];
#pragma unroll
    for (int i = 0; i < 8; i++) acc[i] = f32x4{0.f, 0.f, 0.f, 0.f};

#pragma unroll
    for (int s = 0; s < 5; s++) {
        const int kb = s * 32 + lg * 8;
        bf16x8 af = bf16x8{0, 0, 0, 0, 0, 0, 0, 0};
        if (aval) {
            ushort_t* o = (ushort_t*)&af;
            if (s < 4) {
                const f32x4* p = (const f32x4*)(edge_rep + arow * 128 + kb);
                f32x4 x0 = p[0], x1 = p[1];
#pragma unroll
                for (int j = 0; j < 4; j++) { o[j] = f2bf(x0[j]); o[4 + j] = f2bf(x1[j]); }
            } else if (lg < 2) {
                const f32x4* p = (const f32x4*)(edge_attr + arow * 16 + lg * 8);
                f32x4 x0 = p[0], x1 = p[1];
#pragma unroll
                for (int j = 0; j < 4; j++) { o[j] = f2bf(x0[j]); o[4 + j] = f2bf(x1[j]); }
            }
        }
#pragma unroll
        for (int ct = 0; ct < 8; ct++) {
            const int n = ct * 16 + l16;
            bf16x8 bf = *(const bf16x8*)(BtE + (long)n * 160 + kb);
            acc[ct] = mfma16(af, bf, acc[ct]);
        }
    }

    const int r0 = w * 16 + lg * 4;
#pragma unroll
    for (int ct = 0; ct < 8; ct++) {
#pragma unroll
        for (int r = 0; r < 4; r++) tile[r0 + r][ct * 16 + l16] = acc[ct][r];
    }
    __syncthreads();

    // gather phase: thread (row rr, quarter q) owns cols q*32..q*32+31
    const int rr = tid >> 2;
    const int q = tid & 3;
    const long e = base + rr;
    float vals[32];
    if (e < E) {
        const int si = ei[e];
        const int di = ei[E + e];
        const ushort_t* n1p = n12 + (long)si * 256 + q * 32;
        const ushort_t* n2p = n12 + (long)di * 256 + 128 + q * 32;
#pragma unroll
        for (int i = 0; i < 32; i += 8) {
            bf16x8 v1 = *(const bf16x8*)(n1p + i);
            bf16x8 v2 = *(const bf16x8*)(n2p + i);
            const ushort_t* u1 = (const ushort_t*)&v1;
            const ushort_t* u2 = (const ushort_t*)&v2;
#pragma unroll
            for (int j = 0; j < 8; j++) {
                const int c = q * 32 + i + j;
                vals[i + j] = tile[rr][c] + bf2f(u1[j]) + bf2f(u2[j]) + be[c];
            }
        }
#pragma unroll
        for (int i = 0; i < 32; i += 8) {
            bf16x8 ov;
            ushort_t* o = (ushort_t*)&ov;
#pragma unroll
            for (int j = 0; j < 8; j++) o[j] = f2bf(vals[i + j]);
            *(bf16x8*)(msg + e * 128 + q * 32 + i) = ov;
        }
    } else {
#pragma unroll
        for (int i = 0; i < 32; i++) vals[i] = 0.f;
    }
    // write full msg values back (same cells this thread read — no race)
#pragma unroll
    for (int i = 0; i < 32; i++) tile[rr][q * 32 + i] = vals[i];
    __syncthreads();

    // column stats: thread -> (col c, row-half)
    const int c = tid & 127;
    const int half = tid >> 7;
    float ssum = 0.f, ssq = 0.f;
    const int rbase = half * 32;
#pragma unroll
    for (int r2 = 0; r2 < 32; r2++) {
        const float v = tile[rbase + r2][c];
        ssum += v; ssq += v * v;
    }
    const int slot = blockIdx.x & 63;
    atomicAdd(&st_sum[slot * 128 + c], ssum);
    atomicAdd(&st_sq[slot * 128 + c], ssq);
}

// ---------------------------------------------------------------------------
// BN finalize: a = g*rsqrt(var+eps), c = b - mu*a   (var biased, count=cnt)
// ---------------------------------------------------------------------------
__global__ void finalize_k(
    const float* __restrict__ ssum, const float* __restrict__ ssq,
    const float* __restrict__ g, const float* __restrict__ b,
    float* __restrict__ a, float* __restrict__ c, int ncols, float cnt)
{
    const int n = threadIdx.x;
    if (n >= ncols) return;
    float s = 0.f, s2 = 0.f;
    for (int k = 0; k < 64; k++) { s += ssum[k * ncols + n]; s2 += ssq[k * ncols + n]; }
    const float mu = s / cnt;
    float var = s2 / cnt - mu * mu;
    var = var > 0.f ? var : 0.f;
    const float inv = rsqrtf(var + 1e-5f);
    const float av = g[n] * inv;
    a[n] = av;
    c[n] = b[n] - mu * av;
}

// ---------------------------------------------------------------------------
// Scatter: y[dst[e]] += relu(a0*msg[e]+c0)   (fp32 atomics)
// ---------------------------------------------------------------------------
__global__ __launch_bounds__(256) void scatter_k(
    const ushort_t* __restrict__ msg, const int* __restrict__ ei_dst,
    const float* __restrict__ a0, const float* __restrict__ c0,
    float* __restrict__ y, long E)
{
    const long t = (long)blockIdx.x * 256 + threadIdx.x;
    const long e = t >> 4;
    if (e >= E) return;
    const int q = (int)(t & 15);
    const int d = ei_dst[e];
    bf16x8 v = *(const bf16x8*)(msg + e * 128 + q * 8);
    const ushort_t* u = (const ushort_t*)&v;
    float* yp = y + (long)d * 128 + q * 8;
    const f32x4 av0 = *(const f32x4*)(a0 + q * 8);
    const f32x4 av1 = *(const f32x4*)(a0 + q * 8 + 4);
    const f32x4 cv0 = *(const f32x4*)(c0 + q * 8);
    const f32x4 cv1 = *(const f32x4*)(c0 + q * 8 + 4);
#pragma unroll
    for (int j = 0; j < 4; j++) {
        float m0 = av0[j] * bf2f(u[j]) + cv0[j];
        float m1 = av1[j] * bf2f(u[4 + j]) + cv1[j];
        m0 = m0 > 0.f ? m0 : 0.f;
        m1 = m1 > 0.f ? m1 : 0.f;
        atomicAdd(yp + j, m0);
        atomicAdd(yp + 4 + j, m1);
    }
}

// ---------------------------------------------------------------------------
extern "C" void kernel_launch(void* const* d_in, const int* in_sizes, int n_in,
                              void* d_out, int out_size, void* d_ws, size_t ws_size,
                              hipStream_t stream)
{
    const float* node_rep  = (const float*)d_in[0];
    const float* edge_rep  = (const float*)d_in[1];
    const float* edge_attr = (const float*)d_in[2];
    const int*   ei        = (const int*)d_in[3];
    const float* W1  = (const float*)d_in[4];
    const float* W2  = (const float*)d_in[5];
    const float* W3  = (const float*)d_in[6];
    const float* We  = (const float*)d_in[7];
    const float* be  = (const float*)d_in[8];
    const float* bn_g = (const float*)d_in[9];
    const float* bn_b = (const float*)d_in[10];
    const float* Wm1 = (const float*)d_in[11];
    const float* g1  = (const float*)d_in[12];
    const float* b1  = (const float*)d_in[13];
    const float* Wm2 = (const float*)d_in[14];
    const float* g2  = (const float*)d_in[15];
    const float* b2  = (const float*)d_in[16];
    const float* Wm3 = (const float*)d_in[17];
    const float* bm3 = (const float*)d_in[18];

    const long N = in_sizes[0] / 128;
    const long E = in_sizes[1] / 128;

    char* p = (char*)d_ws;
    float*    y    = (float*)p;    p += (size_t)N * 128 * 4;
    ushort_t* n12  = (ushort_t*)p; p += (size_t)N * 256 * 2;
    ushort_t* msg  = (ushort_t*)p; p += (size_t)E * 128 * 2;
    ushort_t* h1   = (ushort_t*)p; p += (size_t)N * 256 * 2;
    ushort_t* h2   = (ushort_t*)p; p += (size_t)N * 256 * 2;
    ushort_t* BtA  = (ushort_t*)p; p += 32768 * 2;
    ushort_t* BtE  = (ushort_t*)p; p += 20480 * 2;
    ushort_t* BtM1 = (ushort_t*)p; p += 32768 * 2;
    ushort_t* BtM2 = (ushort_t*)p; p += 65536 * 2;
    ushort_t* BtM3 = (ushort_t*)p; p += 32768 * 2;
    float* s0sum = (float*)p; p += 64 * 128 * 4;
    float* s0sq  = (float*)p; p += 64 * 128 * 4;
    float* s1sum = (float*)p; p += 64 * 256 * 4;
    float* s1sq  = (float*)p; p += 64 * 256 * 4;
    float* s2sum = (float*)p; p += 64 * 256 * 4;
    float* s2sq  = (float*)p; p += 64 * 256 * 4;
    float* a0 = (float*)p; p += 128 * 4;
    float* c0 = (float*)p; p += 128 * 4;
    float* a1 = (float*)p; p += 256 * 4;
    float* c1 = (float*)p; p += 256 * 4;
    float* a2 = (float*)p; p += 256 * 4;
    float* c2 = (float*)p; p += 256 * 4;

    hipMemsetAsync(y, 0, (size_t)N * 128 * 4, stream);
    hipMemsetAsync(s0sum, 0, (size_t)(8192 * 2 + 16384 * 4) * 4, stream);

    prep_k<<<720, 256, 0, stream>>>(W1, W2, W3, We, Wm1, Wm2, Wm3,
                                    BtA, BtE, BtM1, BtM2, BtM3);

    const int gN = (int)((N + 63) / 64);
    // K1: n12 = node_rep @ [W1|W2]
    gemm_k<4, 256, 0, false, false><<<gN, 256, 0, stream>>>(
        node_rep, BtA, n12, nullptr, nullptr, nullptr, nullptr, nullptr, (int)N);

    const int gE = (int)((E + 63) / 64);
    edge_k<<<gE, 256, 0, stream>>>(edge_rep, edge_attr, ei, n12, BtE, be,
                                   msg, s0sum, s0sq, E);

    finalize_k<<<1, 128, 0, stream>>>(s0sum, s0sq, bn_g, bn_b, a0, c0, 128, (float)E);

    const int gS = (int)((E * 16 + 255) / 256);
    scatter_k<<<gS, 256, 0, stream>>>(msg, ei + E, a0, c0, y, E);

    // MLP
    gemm_k<4, 256, 0, true, false><<<gN, 256, 0, stream>>>(
        y, BtM1, h1, nullptr, nullptr, nullptr, s1sum, s1sq, (int)N);
    finalize_k<<<1, 256, 0, stream>>>(s1sum, s1sq, g1, b1, a1, c1, 256, (float)N);

    gemm_k<8, 256, 1, true, false><<<gN, 256, 0, stream>>>(
        h1, BtM2, h2, a1, c1, nullptr, s2sum, s2sq, (int)N);
    finalize_k<<<1, 256, 0, stream>>>(s2sum, s2sq, g2, b2, a2, c2, 256, (float)N);

    gemm_k<8, 128, 1, false, true><<<gN, 256, 0, stream>>>(
        h2, BtM3, d_out, a2, c2, bm3, nullptr, nullptr, (int)N);
}